// Round 1
// baseline (286.028 us; speedup 1.0000x reference)
//
#include <hip/hip_runtime.h>
#include <hip/hip_bf16.h>

// DeformableAttention: BS=4, Hq=Wq=64, C=256, M=8, K=4, L=4, CV=32
// SCALES = 64,32,16,8
//
// Pipeline:
//  1. z    = q @ Wz + bz                       [16384,256]
//  2. zo   = z @ Wo + bo                       [16384,256]  (offsets)
//  3. za   = z @ Wa + ba  -> softmax16         [16384,128]  (attn)
//  4. wp_l = feat_l @ Wp + bp  (4 levels)      [BS*h*w,256]
//  5. sampling + scrambled-view attention      [16384,256]  (out_pre, reuses z buf)
//  6. out  = out_pre @ Wm + bm                 [16384,256]
//
// ws layout (bytes):
//   z/out_pre: 0        (16 MB)
//   zo:        16 MB    (16 MB)
//   attn:      32 MB    (8 MB)
//   wp0:       40 MB    (16 MB)
//   wp1:       56 MB    (4 MB)
//   wp2:       60 MB    (1 MB)
//   wp3:       61 MB    (0.25 MB)

#define TILE 64
#define BK 16

__global__ __launch_bounds__(256) void gemm_f32_kernel(
    const float* __restrict__ A, const float* __restrict__ B,
    const float* __restrict__ bias, float* __restrict__ C,
    int Mrows, int N, int K)
{
    __shared__ float As[BK][TILE];
    __shared__ float Bs[BK][TILE];
    const int t  = threadIdx.x;
    const int tx = t & 15, ty = t >> 4;
    const int m0 = blockIdx.y * TILE, n0 = blockIdx.x * TILE;

    float acc[4][4] = {};

    for (int kt = 0; kt < K; kt += BK) {
        // A tile: 64 rows x 16 k. thread t loads float4: row=t>>2, kcols=(t&3)*4
        {
            const int r  = t >> 2;
            const int kc = (t & 3) * 4;
            const float4 v = *(const float4*)(A + (size_t)(m0 + r) * K + kt + kc);
            As[kc + 0][r] = v.x; As[kc + 1][r] = v.y;
            As[kc + 2][r] = v.z; As[kc + 3][r] = v.w;
        }
        // B tile: 16 k x 64 n. thread t loads float4: kk=t>>4, ncols=(t&15)*4
        {
            const int kk = t >> 4;
            const int nc = (t & 15) * 4;
            const float4 v = *(const float4*)(B + (size_t)(kt + kk) * N + n0 + nc);
            *(float4*)&Bs[kk][nc] = v;
        }
        __syncthreads();
        #pragma unroll
        for (int kk = 0; kk < BK; ++kk) {
            const float4 a4 = *(const float4*)&As[kk][ty * 4];
            const float4 b4 = *(const float4*)&Bs[kk][tx * 4];
            const float a[4] = {a4.x, a4.y, a4.z, a4.w};
            const float b[4] = {b4.x, b4.y, b4.z, b4.w};
            #pragma unroll
            for (int i = 0; i < 4; ++i)
                #pragma unroll
                for (int j = 0; j < 4; ++j)
                    acc[i][j] += a[i] * b[j];
        }
        __syncthreads();
    }

    const float4 b4 = *(const float4*)(bias + n0 + tx * 4);
    #pragma unroll
    for (int i = 0; i < 4; ++i) {
        const int row = m0 + ty * 4 + i;
        float4 o;
        o.x = acc[i][0] + b4.x; o.y = acc[i][1] + b4.y;
        o.z = acc[i][2] + b4.z; o.w = acc[i][3] + b4.w;
        *(float4*)(C + (size_t)row * N + n0 + tx * 4) = o;
    }
}

// softmax over groups of 16 contiguous floats, in place
__global__ __launch_bounds__(256) void softmax16_kernel(float* __restrict__ za, int ngroups)
{
    const int g = blockIdx.x * 256 + threadIdx.x;
    if (g >= ngroups) return;
    float* p = za + (size_t)g * 16;
    float v[16];
    #pragma unroll
    for (int i = 0; i < 16; ++i) v[i] = p[i];
    float mx = v[0];
    #pragma unroll
    for (int i = 1; i < 16; ++i) mx = fmaxf(mx, v[i]);
    float s = 0.f;
    #pragma unroll
    for (int i = 0; i < 16; ++i) { v[i] = __expf(v[i] - mx) ; s += v[i]; }
    // use expf-compatible precision: recompute with expf to be safe
    // (redone below with expf to match reference numerics closely)
    s = 0.f;
    #pragma unroll
    for (int i = 0; i < 16; ++i) { v[i] = expf(p[i] - mx); s += v[i]; }
    const float inv = 1.f / s;
    #pragma unroll
    for (int i = 0; i < 16; ++i) p[i] = v[i] * inv;
}

// one thread per output element of out_pre [BS,64,64,256]
__global__ __launch_bounds__(256) void sample_kernel(
    const float* __restrict__ zo,   // [BS,64,64,256]
    const float* __restrict__ attn, // [BS,4096,128] (m*16+s)
    const float* __restrict__ ref,  // [BS,64,64,2]
    const float* __restrict__ wp0, const float* __restrict__ wp1,
    const float* __restrict__ wp2, const float* __restrict__ wp3,
    float* __restrict__ outp)       // [BS,64,64,256]
{
    const int o  = blockIdx.x * 256 + threadIdx.x;
    const int c   = o & 255;
    const int x3  = (o >> 8) & 63;
    const int y3  = (o >> 14) & 63;
    const int b   = o >> 20;
    const int m   = c >> 5;
    const int cv3 = c & 31;

    const int p  = y3 * 64 + x3;
    const int k  = p >> 10;
    const int qx = (p >> 4) & 63;
    const int ya = p & 15;
    const int l  = (cv3 >> 1) & 3;
    const int yb = cv3 >> 3;
    const int hi = cv3 & 1;
    const int qy = ya * 4 + yb;

    const int hw = 64 >> l;
    const float* wp = (l == 0) ? wp0 : (l == 1) ? wp1 : (l == 2) ? wp2 : wp3;

    // learned offset
    const size_t qoff = (size_t)b * 4096 + qy * 64 + qx;
    const float* zop = zo + qoff * 256 + (size_t)(((m * 4 + l) * 4 + k) * 2);
    const float offx = zop[0], offy = zop[1];

    // reference point: tile(M,1,1,1) quirk -> batch index = (b*M+m) % BS = m & 3
    const int rb = m & 3;
    const float* rp = ref + ((size_t)rb * 4096 + qy * 64 + qx) * 2;

    const float fw = (float)hw;
    const float px = rp[0] * (fw - 1.f) + offx;
    const float py = rp[1] * (fw - 1.f) + offy;
    const float gx = 2.f * px / (fw - 1.f) - 1.f;
    const float gy = 2.f * py / (fw - 1.f) - 1.f;
    const float xim = (gx + 1.f) * (fw * 0.5f) - 0.5f;
    const float yim = (gy + 1.f) * (fw * 0.5f) - 0.5f;

    const float x0f = floorf(xim), y0f = floorf(yim);
    const float wx1 = xim - x0f, wy1 = yim - y0f;
    const float wx0 = 1.f - wx1, wy0 = 1.f - wy1;
    const int ix0 = (int)x0f, iy0 = (int)y0f;

    const int chb = m * 32 + hi * 16;

    float4 a0 = {0,0,0,0}, a1 = {0,0,0,0}, a2 = {0,0,0,0}, a3 = {0,0,0,0};

    #pragma unroll
    for (int tapi = 0; tapi < 4; ++tapi) {
        const int iy = iy0 + (tapi >> 1);
        const int ix = ix0 + (tapi & 1);
        const float wt = ((tapi >> 1) ? wy1 : wy0) * ((tapi & 1) ? wx1 : wx0);
        if (iy < 0 || iy >= hw || ix < 0 || ix >= hw) continue;
        const float4* tp = (const float4*)(wp + (((size_t)b * hw + iy) * hw + ix) * 256 + chb);
        const float4 t0 = tp[0], t1 = tp[1], t2 = tp[2], t3 = tp[3];
        a0.x += wt * t0.x; a0.y += wt * t0.y; a0.z += wt * t0.z; a0.w += wt * t0.w;
        a1.x += wt * t1.x; a1.y += wt * t1.y; a1.z += wt * t1.z; a1.w += wt * t1.w;
        a2.x += wt * t2.x; a2.y += wt * t2.y; a2.z += wt * t2.z; a2.w += wt * t2.w;
        a3.x += wt * t3.x; a3.y += wt * t3.y; a3.z += wt * t3.z; a3.w += wt * t3.w;
    }

    const float4* ap = (const float4*)(attn + ((size_t)b * 4096 + p) * 128 + m * 16);
    const float4 w0 = ap[0], w1 = ap[1], w2 = ap[2], w3 = ap[3];

    float r = a0.x * w0.x + a0.y * w0.y + a0.z * w0.z + a0.w * w0.w
            + a1.x * w1.x + a1.y * w1.y + a1.z * w1.z + a1.w * w1.w
            + a2.x * w2.x + a2.y * w2.y + a2.z * w2.z + a2.w * w2.w
            + a3.x * w3.x + a3.y * w3.y + a3.z * w3.z + a3.w * w3.w;

    outp[o] = r;
}

extern "C" void kernel_launch(void* const* d_in, const int* in_sizes, int n_in,
                              void* d_out, int out_size, void* d_ws, size_t ws_size,
                              hipStream_t stream)
{
    const float* q   = (const float*)d_in[0];
    const float* ref = (const float*)d_in[1];
    const float* f0  = (const float*)d_in[2];
    const float* f1  = (const float*)d_in[3];
    const float* f2  = (const float*)d_in[4];
    const float* f3  = (const float*)d_in[5];
    const float* Wz  = (const float*)d_in[6];
    const float* bz  = (const float*)d_in[7];
    const float* Wo  = (const float*)d_in[8];
    const float* bo  = (const float*)d_in[9];
    const float* Wa  = (const float*)d_in[10];
    const float* ba  = (const float*)d_in[11];
    const float* Wp  = (const float*)d_in[12];
    const float* bp  = (const float*)d_in[13];
    const float* Wm  = (const float*)d_in[14];
    const float* bm  = (const float*)d_in[15];
    float* out = (float*)d_out;

    char* ws = (char*)d_ws;
    float* z    = (float*)(ws + (size_t)0);
    float* zo   = (float*)(ws + ((size_t)16 << 20));
    float* attn = (float*)(ws + ((size_t)32 << 20));
    float* wp0  = (float*)(ws + ((size_t)40 << 20));
    float* wp1  = (float*)(ws + ((size_t)56 << 20));
    float* wp2  = (float*)(ws + ((size_t)60 << 20));
    float* wp3  = (float*)(ws + ((size_t)61 << 20));
    float* outp = z;  // reuse: z dead after za GEMM

    const dim3 blk(256);

    // 1. z = q @ Wz + bz
    gemm_f32_kernel<<<dim3(4, 256), blk, 0, stream>>>(q, Wz, bz, z, 16384, 256, 256);
    // 2. zo = z @ Wo + bo
    gemm_f32_kernel<<<dim3(4, 256), blk, 0, stream>>>(z, Wo, bo, zo, 16384, 256, 256);
    // 3. za = z @ Wa + ba ; softmax16 in place
    gemm_f32_kernel<<<dim3(2, 256), blk, 0, stream>>>(z, Wa, ba, attn, 16384, 128, 256);
    softmax16_kernel<<<dim3(512), blk, 0, stream>>>(attn, 131072);
    // 4. wp_l = feat_l @ Wp + bp
    gemm_f32_kernel<<<dim3(4, 256), blk, 0, stream>>>(f0, Wp, bp, wp0, 16384, 256, 256);
    gemm_f32_kernel<<<dim3(4,  64), blk, 0, stream>>>(f1, Wp, bp, wp1,  4096, 256, 256);
    gemm_f32_kernel<<<dim3(4,  16), blk, 0, stream>>>(f2, Wp, bp, wp2,  1024, 256, 256);
    gemm_f32_kernel<<<dim3(4,   4), blk, 0, stream>>>(f3, Wp, bp, wp3,   256, 256, 256);
    // 5. sampling + scrambled attention contraction -> out_pre (overwrites z)
    sample_kernel<<<dim3(16384), blk, 0, stream>>>(zo, attn, ref, wp0, wp1, wp2, wp3, outp);
    // 6. out = out_pre @ Wm + bm
    gemm_f32_kernel<<<dim3(4, 256), blk, 0, stream>>>(outp, Wm, bm, out, 16384, 256, 256);
}

// Round 2
// 251.533 us; speedup vs baseline: 1.1371x; 1.1371x over previous
//
#include <hip/hip_runtime.h>
#include <hip/hip_bf16.h>

// DeformableAttention: BS=4, Hq=Wq=64, C=256, M=8, K=4, L=4, CV=32
// SCALES = 64,32,16,8
//
// Pipeline (all GEMMs via bf16 MFMA 16x16x32; wp & final use bf16x3 split for ~f32 acc):
//  1. z   = bf16( q@Wz + bz )          [16384,256] bf16
//  2. zo  = bf16( z@Wo + bo )          [16384,256] bf16 (offsets)
//  3. za  = bf16( z@Wa + ba )          [16384,128] bf16
//  4. softmax16: za -> attn_t          [b][m][4096][16] f32
//  5. wp_l = feat_l@Wp + bp (split)    f32
//  6. sample (level-uniform waves)     out_pre f32 [16384,256]
//  7. out = out_pre@Wm + bm (split)    f32 -> d_out
//
// ws layout (MB): z@0(8) za@8(4) [12..16 free] zo@16(8) [24..28 free]
//   attn_t@28(8) wp0@36(16) wp1@52(4) wp2@56(1) wp3@57(0.25)
//   out_pre@0(16) (overwrites z/za after they are dead). Peak 57.25 MB.

typedef __attribute__((ext_vector_type(8))) short short8;
typedef __attribute__((ext_vector_type(4))) float f32x4;

__device__ __forceinline__ short f2bf(float x) {
    unsigned u = __builtin_bit_cast(unsigned, x);
    unsigned r = (u + 0x7fffu + ((u >> 16) & 1u)) >> 16;
    return (short)r;
}
__device__ __forceinline__ float bf2f(short s) {
    unsigned u = ((unsigned)(unsigned short)s) << 16;
    return __builtin_bit_cast(float, u);
}

// ---------------------------------------------------------------------------
// MFMA GEMM: C[rows x N] = A[rows x 256] @ B[256 x N] + bias
// AT in {float, short(bf16)}; OT in {float, short(bf16)}; SPLIT -> bf16x3.
// Block: 256 thr = 4 waves, tile 128x128, BK=32, single-buffer LDS.
// ---------------------------------------------------------------------------
template<typename AT, typename OT, bool SPLIT>
__global__ __launch_bounds__(256) void gemm_mfma(
    const AT* __restrict__ A, const float* __restrict__ B,
    const float* __restrict__ bias, OT* __restrict__ C, int N)
{
    constexpr int LDT = 40;  // LDS row stride (elems): 80B -> conflict-free-ish, 16B-aligned
    __shared__ short As[(SPLIT ? 2 : 1) * 128 * LDT];
    __shared__ short Bs[(SPLIT ? 2 : 1) * 128 * LDT];
    short* Asl = As + 128 * LDT;
    short* Bsl = Bs + 128 * LDT;

    const int t    = threadIdx.x;
    const int lane = t & 63, wid = t >> 6;
    const int wr = wid >> 1, wc = wid & 1;
    const int lr = lane & 15, lkb = (lane >> 4) * 8;
    const int m0 = blockIdx.y * 128, n0 = blockIdx.x * 128;

    const int arow = t >> 1, akoff = (t & 1) * 16;
    const int bn = t & 127, bkoff = (t >> 7) * 16;

    f32x4 acc[4][4] = {};

    for (int kt = 0; kt < 256; kt += 32) {
        // ---- stage A tile [128 x 32] ----
        if constexpr (sizeof(AT) == 4) {
            const float* ap = (const float*)A + (size_t)(m0 + arow) * 256 + kt + akoff;
            float v[16];
            #pragma unroll
            for (int i = 0; i < 4; ++i) {
                float4 f = ((const float4*)ap)[i];
                v[4*i] = f.x; v[4*i+1] = f.y; v[4*i+2] = f.z; v[4*i+3] = f.w;
            }
            short8 h0, h1;
            #pragma unroll
            for (int i = 0; i < 8; ++i) { h0[i] = f2bf(v[i]); h1[i] = f2bf(v[8+i]); }
            *(short8*)&As[arow*LDT + akoff]     = h0;
            *(short8*)&As[arow*LDT + akoff + 8] = h1;
            if constexpr (SPLIT) {
                short8 l0, l1;
                #pragma unroll
                for (int i = 0; i < 8; ++i) {
                    l0[i] = f2bf(v[i]   - bf2f(h0[i]));
                    l1[i] = f2bf(v[8+i] - bf2f(h1[i]));
                }
                *(short8*)&Asl[arow*LDT + akoff]     = l0;
                *(short8*)&Asl[arow*LDT + akoff + 8] = l1;
            }
        } else {
            const short* ap = (const short*)A + (size_t)(m0 + arow) * 256 + kt + akoff;
            *(short8*)&As[arow*LDT + akoff]     = ((const short8*)ap)[0];
            *(short8*)&As[arow*LDT + akoff + 8] = ((const short8*)ap)[1];
        }
        // ---- stage B tile [32 x 128] transposed -> Bs[n][k] ----
        {
            const float* bp = B + (size_t)(kt + bkoff) * N + n0 + bn;
            float v[16];
            #pragma unroll
            for (int i = 0; i < 16; ++i) v[i] = bp[(size_t)i * N];
            short8 h0, h1;
            #pragma unroll
            for (int i = 0; i < 8; ++i) { h0[i] = f2bf(v[i]); h1[i] = f2bf(v[8+i]); }
            *(short8*)&Bs[bn*LDT + bkoff]     = h0;
            *(short8*)&Bs[bn*LDT + bkoff + 8] = h1;
            if constexpr (SPLIT) {
                short8 l0, l1;
                #pragma unroll
                for (int i = 0; i < 8; ++i) {
                    l0[i] = f2bf(v[i]   - bf2f(h0[i]));
                    l1[i] = f2bf(v[8+i] - bf2f(h1[i]));
                }
                *(short8*)&Bsl[bn*LDT + bkoff]     = l0;
                *(short8*)&Bsl[bn*LDT + bkoff + 8] = l1;
            }
        }
        __syncthreads();

        short8 af[4], bfh[4];
        #pragma unroll
        for (int m = 0; m < 4; ++m)
            af[m] = *(const short8*)&As[(wr*64 + m*16 + lr)*LDT + lkb];
        #pragma unroll
        for (int n = 0; n < 4; ++n)
            bfh[n] = *(const short8*)&Bs[(wc*64 + n*16 + lr)*LDT + lkb];
        if constexpr (!SPLIT) {
            #pragma unroll
            for (int m = 0; m < 4; ++m)
                #pragma unroll
                for (int n = 0; n < 4; ++n)
                    acc[m][n] = __builtin_amdgcn_mfma_f32_16x16x32_bf16(af[m], bfh[n], acc[m][n], 0, 0, 0);
        } else {
            short8 afl[4], bfl[4];
            #pragma unroll
            for (int m = 0; m < 4; ++m)
                afl[m] = *(const short8*)&Asl[(wr*64 + m*16 + lr)*LDT + lkb];
            #pragma unroll
            for (int n = 0; n < 4; ++n)
                bfl[n] = *(const short8*)&Bsl[(wc*64 + n*16 + lr)*LDT + lkb];
            #pragma unroll
            for (int m = 0; m < 4; ++m)
                #pragma unroll
                for (int n = 0; n < 4; ++n) {
                    acc[m][n] = __builtin_amdgcn_mfma_f32_16x16x32_bf16(af[m],  bfh[n], acc[m][n], 0, 0, 0);
                    acc[m][n] = __builtin_amdgcn_mfma_f32_16x16x32_bf16(af[m],  bfl[n], acc[m][n], 0, 0, 0);
                    acc[m][n] = __builtin_amdgcn_mfma_f32_16x16x32_bf16(afl[m], bfh[n], acc[m][n], 0, 0, 0);
                }
        }
        __syncthreads();
    }

    // ---- epilogue: D[row][col], col = lane&15, row = (lane>>4)*4 + r ----
    #pragma unroll
    for (int n = 0; n < 4; ++n) {
        const int col = n0 + wc*64 + n*16 + lr;
        const float bv = bias[col];
        #pragma unroll
        for (int m = 0; m < 4; ++m) {
            #pragma unroll
            for (int r = 0; r < 4; ++r) {
                const int row = m0 + wr*64 + m*16 + (lane >> 4)*4 + r;
                const float v = acc[m][n][r] + bv;
                if constexpr (sizeof(OT) == 4)
                    ((float*)C)[(size_t)row * N + col] = v;
                else
                    ((short*)C)[(size_t)row * N + col] = f2bf(v);
            }
        }
    }
}

// softmax over s=16 for each (b,m,qpos); za bf16 [b][q][128] -> attn_t f32 [b][m][q][16]
__global__ __launch_bounds__(256) void softmax2(const short* __restrict__ za, float* __restrict__ attn_t)
{
    const int tid  = blockIdx.x * 256 + threadIdx.x;  // 131072
    const int qpos = tid & 4095;
    const int m    = (tid >> 12) & 7;
    const int b    = tid >> 15;
    const short* zp = za + ((size_t)(b * 4096 + qpos)) * 128 + m * 16;
    float v[16];
    #pragma unroll
    for (int i = 0; i < 16; ++i) v[i] = bf2f(zp[i]);
    float mx = v[0];
    #pragma unroll
    for (int i = 1; i < 16; ++i) mx = fmaxf(mx, v[i]);
    float s = 0.f;
    #pragma unroll
    for (int i = 0; i < 16; ++i) { v[i] = expf(v[i] - mx); s += v[i]; }
    const float inv = 1.f / s;
    float* op = attn_t + (((size_t)b * 8 + m) * 4096 + qpos) * 16;
    #pragma unroll
    for (int i = 0; i < 16; ++i) op[i] = v[i] * inv;
}

// sample: wave = (b,y3,m,yb), lane = x3; loops l=0..3, handles both hi halves (32 ch).
__global__ __launch_bounds__(256) void sample2(
    const short* __restrict__ zo,      // bf16 [b][qy][qx][256]
    const float* __restrict__ attn_t,  // f32 [b][m][4096][16]
    const float* __restrict__ ref,     // f32 [BS][64][64][2]
    const float* __restrict__ wp0, const float* __restrict__ wp1,
    const float* __restrict__ wp2, const float* __restrict__ wp3,
    float* __restrict__ outp)          // f32 [b][p][256]
{
    const int lane = threadIdx.x & 63;
    const int W    = blockIdx.x * 4 + (threadIdx.x >> 6);  // 13 bits
    const int yb = W & 3;
    const int m  = (W >> 2) & 7;
    const int y3 = (W >> 5) & 63;
    const int b  = W >> 11;
    const int x3 = lane;

    const int p  = y3 * 64 + x3;
    const int k  = p >> 10;
    const int qx = (p >> 4) & 63;
    const int ya = p & 15;
    const int qy = ya * 4 + yb;
    const int rb = m & 3;

    const float2 rr = *(const float2*)(ref + ((size_t)rb * 4096 + qy * 64 + qx) * 2);

    float w[16];
    {
        const float4* ap = (const float4*)(attn_t + (((size_t)b * 8 + m) * 4096 + p) * 16);
        #pragma unroll
        for (int i = 0; i < 4; ++i) {
            float4 f = ap[i];
            w[4*i] = f.x; w[4*i+1] = f.y; w[4*i+2] = f.z; w[4*i+3] = f.w;
        }
    }

    const short* zrow = zo + ((size_t)(b * 4096 + qy * 64 + qx)) * 256 + m * 32 + k * 2;
    const float* wps[4] = {wp0, wp1, wp2, wp3};

    float out[8];
    #pragma unroll
    for (int l = 0; l < 4; ++l) {
        const int hw = 64 >> l;
        const float* wp = wps[l];
        const float offx = bf2f(zrow[l * 8 + 0]);
        const float offy = bf2f(zrow[l * 8 + 1]);

        const float fw  = (float)hw;
        const float px  = rr.x * (fw - 1.f) + offx;
        const float py  = rr.y * (fw - 1.f) + offy;
        const float gx  = 2.f * px / (fw - 1.f) - 1.f;
        const float gy  = 2.f * py / (fw - 1.f) - 1.f;
        const float xim = (gx + 1.f) * (fw * 0.5f) - 0.5f;
        const float yim = (gy + 1.f) * (fw * 0.5f) - 0.5f;

        const float x0f = floorf(xim), y0f = floorf(yim);
        const float wx1 = xim - x0f, wy1 = yim - y0f;
        const float wx0 = 1.f - wx1, wy0 = 1.f - wy1;
        const int ix0 = (int)x0f, iy0 = (int)y0f;

        float acc[32];
        #pragma unroll
        for (int i = 0; i < 32; ++i) acc[i] = 0.f;

        #pragma unroll
        for (int tapi = 0; tapi < 4; ++tapi) {
            const int iy = iy0 + (tapi >> 1);
            const int ix = ix0 + (tapi & 1);
            const float wt = ((tapi >> 1) ? wy1 : wy0) * ((tapi & 1) ? wx1 : wx0);
            if (iy < 0 || iy >= hw || ix < 0 || ix >= hw) continue;
            const float4* tp = (const float4*)(wp + (((size_t)b * hw + iy) * hw + ix) * 256 + m * 32);
            #pragma unroll
            for (int j = 0; j < 8; ++j) {
                const float4 f = tp[j];
                acc[4*j]   += wt * f.x; acc[4*j+1] += wt * f.y;
                acc[4*j+2] += wt * f.z; acc[4*j+3] += wt * f.w;
            }
        }
        float d0 = 0.f, d1 = 0.f;
        #pragma unroll
        for (int s = 0; s < 16; ++s) { d0 += acc[s] * w[s]; d1 += acc[16 + s] * w[s]; }
        out[l * 2 + 0] = d0;
        out[l * 2 + 1] = d1;
    }

    float4* op = (float4*)(outp + ((size_t)b * 4096 + p) * 256 + m * 32 + yb * 8);
    op[0] = make_float4(out[0], out[1], out[2], out[3]);
    op[1] = make_float4(out[4], out[5], out[6], out[7]);
}

extern "C" void kernel_launch(void* const* d_in, const int* in_sizes, int n_in,
                              void* d_out, int out_size, void* d_ws, size_t ws_size,
                              hipStream_t stream)
{
    const float* q   = (const float*)d_in[0];
    const float* ref = (const float*)d_in[1];
    const float* f0  = (const float*)d_in[2];
    const float* f1  = (const float*)d_in[3];
    const float* f2  = (const float*)d_in[4];
    const float* f3  = (const float*)d_in[5];
    const float* Wz  = (const float*)d_in[6];
    const float* bz  = (const float*)d_in[7];
    const float* Wo  = (const float*)d_in[8];
    const float* bo  = (const float*)d_in[9];
    const float* Wa  = (const float*)d_in[10];
    const float* ba  = (const float*)d_in[11];
    const float* Wp  = (const float*)d_in[12];
    const float* bp  = (const float*)d_in[13];
    const float* Wm  = (const float*)d_in[14];
    const float* bm  = (const float*)d_in[15];
    float* out = (float*)d_out;

    char* ws = (char*)d_ws;
    short* z      = (short*)(ws + ((size_t)0));         // bf16 8MB
    short* za     = (short*)(ws + ((size_t)8  << 20));  // bf16 4MB
    short* zo     = (short*)(ws + ((size_t)16 << 20));  // bf16 8MB
    float* attn_t = (float*)(ws + ((size_t)28 << 20));  // f32 8MB
    float* wp0    = (float*)(ws + ((size_t)36 << 20));  // f32 16MB
    float* wp1    = (float*)(ws + ((size_t)52 << 20));  // f32 4MB
    float* wp2    = (float*)(ws + ((size_t)56 << 20));  // f32 1MB
    float* wp3    = (float*)(ws + ((size_t)57 << 20));  // f32 0.25MB
    float* outp   = (float*)(ws + ((size_t)0));         // f32 16MB (z/za dead)

    const dim3 blk(256);

    // 1. z = bf16(q @ Wz + bz)
    gemm_mfma<float, short, false><<<dim3(2, 128), blk, 0, stream>>>(q, Wz, bz, z, 256);
    // 2. zo = bf16(z @ Wo + bo)
    gemm_mfma<short, short, false><<<dim3(2, 128), blk, 0, stream>>>(z, Wo, bo, zo, 256);
    // 3. za = bf16(z @ Wa + ba)
    gemm_mfma<short, short, false><<<dim3(1, 128), blk, 0, stream>>>(z, Wa, ba, za, 128);
    // 4. softmax -> attn_t [b][m][q][16]
    softmax2<<<dim3(512), blk, 0, stream>>>(za, attn_t);
    // 5. wp_l = feat_l @ Wp + bp (bf16x3 split)
    gemm_mfma<float, float, true><<<dim3(2, 128), blk, 0, stream>>>(f0, Wp, bp, wp0, 256);
    gemm_mfma<float, float, true><<<dim3(2,  32), blk, 0, stream>>>(f1, Wp, bp, wp1, 256);
    gemm_mfma<float, float, true><<<dim3(2,   8), blk, 0, stream>>>(f2, Wp, bp, wp2, 256);
    gemm_mfma<float, float, true><<<dim3(2,   2), blk, 0, stream>>>(f3, Wp, bp, wp3, 256);
    // 6. sampling -> out_pre (overwrites z/za region)
    sample2<<<dim3(2048), blk, 0, stream>>>(zo, attn_t, ref, wp0, wp1, wp2, wp3, outp);
    // 7. out = out_pre @ Wm + bm (bf16x3 split)
    gemm_mfma<float, float, true><<<dim3(2, 128), blk, 0, stream>>>(outp, Wm, bm, out, 256);
}

// Round 3
// 142.694 us; speedup vs baseline: 2.0045x; 1.7627x over previous
//
#include <hip/hip_runtime.h>
#include <hip/hip_bf16.h>

// DeformableAttention: BS=4, Hq=Wq=64, C=256, M=8, K=4, L=4, CV=32
// SCALES = 64,32,16,8
//
//  1. z   = bf16( q@Wz + bz )          [16384,256] bf16
//  2. zo  = bf16( z@Wo + bo )          [16384,256] bf16 (offsets)
//  3. za  = bf16( z@Wa + ba )          [16384,128] bf16
//  4. softmax16: za -> attn_t          [b][m][4096][16] f32
//  5. wp_l = feat_l@Wp + bp (split)    f32, ONE dispatch for all 4 levels
//  6. sample: block per (b,qy,qx), tid=m*32+l*8+k*2+hi  -> out_pre f32
//  7. out = out_pre@Wm + bm (split)    f32 -> d_out
//
// ws layout (MB): z@0(8) za@8(4) zo@16(8) attn_t@28(8)
//   wp0@36(16) wp1@52(4) wp2@56(1) wp3@57(0.25); out_pre@0(16). Peak 57.25 MB.

typedef __attribute__((ext_vector_type(8))) short short8;
typedef __attribute__((ext_vector_type(4))) float f32x4;

constexpr int LDT = 40;  // LDS row stride (bf16 elems)

__device__ __forceinline__ short f2bf(float x) {
    unsigned u = __builtin_bit_cast(unsigned, x);
    unsigned r = (u + 0x7fffu + ((u >> 16) & 1u)) >> 16;
    return (short)r;
}
__device__ __forceinline__ float bf2f(short s) {
    unsigned u = ((unsigned)(unsigned short)s) << 16;
    return __builtin_bit_cast(float, u);
}

// ---------------------------------------------------------------------------
// GEMM body: C[tile 128x128 at (m0,n0)] = A[rows x 256] @ B[256 x N] + bias
// ---------------------------------------------------------------------------
template<typename AT, typename OT, bool SPLIT>
__device__ __forceinline__ void gemm_body(
    short* __restrict__ As, short* __restrict__ Bs,
    const AT* __restrict__ A, const float* __restrict__ B,
    const float* __restrict__ bias, OT* __restrict__ C,
    int N, int m0, int n0)
{
    short* Asl = As + 128 * LDT;
    short* Bsl = Bs + 128 * LDT;

    const int t    = threadIdx.x;
    const int lane = t & 63, wid = t >> 6;
    const int wr = wid >> 1, wc = wid & 1;
    const int lr = lane & 15, lkb = (lane >> 4) * 8;

    const int arow = t >> 1, akoff = (t & 1) * 16;
    const int bn = t & 127, bkoff = (t >> 7) * 16;

    f32x4 acc[4][4] = {};

    for (int kt = 0; kt < 256; kt += 32) {
        if constexpr (sizeof(AT) == 4) {
            const float* ap = (const float*)A + (size_t)(m0 + arow) * 256 + kt + akoff;
            float v[16];
            #pragma unroll
            for (int i = 0; i < 4; ++i) {
                float4 f = ((const float4*)ap)[i];
                v[4*i] = f.x; v[4*i+1] = f.y; v[4*i+2] = f.z; v[4*i+3] = f.w;
            }
            short8 h0, h1;
            #pragma unroll
            for (int i = 0; i < 8; ++i) { h0[i] = f2bf(v[i]); h1[i] = f2bf(v[8+i]); }
            *(short8*)&As[arow*LDT + akoff]     = h0;
            *(short8*)&As[arow*LDT + akoff + 8] = h1;
            if constexpr (SPLIT) {
                short8 l0, l1;
                #pragma unroll
                for (int i = 0; i < 8; ++i) {
                    l0[i] = f2bf(v[i]   - bf2f(h0[i]));
                    l1[i] = f2bf(v[8+i] - bf2f(h1[i]));
                }
                *(short8*)&Asl[arow*LDT + akoff]     = l0;
                *(short8*)&Asl[arow*LDT + akoff + 8] = l1;
            }
        } else {
            const short* ap = (const short*)A + (size_t)(m0 + arow) * 256 + kt + akoff;
            *(short8*)&As[arow*LDT + akoff]     = ((const short8*)ap)[0];
            *(short8*)&As[arow*LDT + akoff + 8] = ((const short8*)ap)[1];
        }
        {
            const float* bp = B + (size_t)(kt + bkoff) * N + n0 + bn;
            float v[16];
            #pragma unroll
            for (int i = 0; i < 16; ++i) v[i] = bp[(size_t)i * N];
            short8 h0, h1;
            #pragma unroll
            for (int i = 0; i < 8; ++i) { h0[i] = f2bf(v[i]); h1[i] = f2bf(v[8+i]); }
            *(short8*)&Bs[bn*LDT + bkoff]     = h0;
            *(short8*)&Bs[bn*LDT + bkoff + 8] = h1;
            if constexpr (SPLIT) {
                short8 l0, l1;
                #pragma unroll
                for (int i = 0; i < 8; ++i) {
                    l0[i] = f2bf(v[i]   - bf2f(h0[i]));
                    l1[i] = f2bf(v[8+i] - bf2f(h1[i]));
                }
                *(short8*)&Bsl[bn*LDT + bkoff]     = l0;
                *(short8*)&Bsl[bn*LDT + bkoff + 8] = l1;
            }
        }
        __syncthreads();

        short8 af[4], bfh[4];
        #pragma unroll
        for (int m = 0; m < 4; ++m)
            af[m] = *(const short8*)&As[(wr*64 + m*16 + lr)*LDT + lkb];
        #pragma unroll
        for (int n = 0; n < 4; ++n)
            bfh[n] = *(const short8*)&Bs[(wc*64 + n*16 + lr)*LDT + lkb];
        if constexpr (!SPLIT) {
            #pragma unroll
            for (int m = 0; m < 4; ++m)
                #pragma unroll
                for (int n = 0; n < 4; ++n)
                    acc[m][n] = __builtin_amdgcn_mfma_f32_16x16x32_bf16(af[m], bfh[n], acc[m][n], 0, 0, 0);
        } else {
            short8 afl[4], bfl[4];
            #pragma unroll
            for (int m = 0; m < 4; ++m)
                afl[m] = *(const short8*)&Asl[(wr*64 + m*16 + lr)*LDT + lkb];
            #pragma unroll
            for (int n = 0; n < 4; ++n)
                bfl[n] = *(const short8*)&Bsl[(wc*64 + n*16 + lr)*LDT + lkb];
            #pragma unroll
            for (int m = 0; m < 4; ++m)
                #pragma unroll
                for (int n = 0; n < 4; ++n) {
                    acc[m][n] = __builtin_amdgcn_mfma_f32_16x16x32_bf16(af[m],  bfh[n], acc[m][n], 0, 0, 0);
                    acc[m][n] = __builtin_amdgcn_mfma_f32_16x16x32_bf16(af[m],  bfl[n], acc[m][n], 0, 0, 0);
                    acc[m][n] = __builtin_amdgcn_mfma_f32_16x16x32_bf16(afl[m], bfh[n], acc[m][n], 0, 0, 0);
                }
        }
        __syncthreads();
    }

    #pragma unroll
    for (int n = 0; n < 4; ++n) {
        const int col = n0 + wc*64 + n*16 + lr;
        const float bv = bias[col];
        #pragma unroll
        for (int m = 0; m < 4; ++m) {
            #pragma unroll
            for (int r = 0; r < 4; ++r) {
                const int row = m0 + wr*64 + m*16 + (lane >> 4)*4 + r;
                const float v = acc[m][n][r] + bv;
                if constexpr (sizeof(OT) == 4)
                    ((float*)C)[(size_t)row * N + col] = v;
                else
                    ((short*)C)[(size_t)row * N + col] = f2bf(v);
            }
        }
    }
}

template<typename AT, typename OT, bool SPLIT>
__global__ __launch_bounds__(256) void gemm_mfma(
    const AT* __restrict__ A, const float* __restrict__ B,
    const float* __restrict__ bias, OT* __restrict__ C, int N)
{
    __shared__ short As[(SPLIT ? 2 : 1) * 128 * LDT];
    __shared__ short Bs[(SPLIT ? 2 : 1) * 128 * LDT];
    gemm_body<AT, OT, SPLIT>(As, Bs, A, B, bias, C, N, blockIdx.y * 128, blockIdx.x * 128);
}

// all 4 wp GEMMs in one dispatch; blockIdx.y selects level+tile
__global__ __launch_bounds__(256) void gemm_wp_all(
    const float* __restrict__ f0, const float* __restrict__ f1,
    const float* __restrict__ f2, const float* __restrict__ f3,
    const float* __restrict__ B, const float* __restrict__ bias,
    float* __restrict__ w0, float* __restrict__ w1,
    float* __restrict__ w2, float* __restrict__ w3)
{
    __shared__ short As[2 * 128 * LDT];
    __shared__ short Bs[2 * 128 * LDT];
    const int by = blockIdx.y;
    const float* A; float* C; int m0;
    if      (by < 128) { A = f0; C = w0; m0 = by * 128; }
    else if (by < 160) { A = f1; C = w1; m0 = (by - 128) * 128; }
    else if (by < 168) { A = f2; C = w2; m0 = (by - 160) * 128; }
    else               { A = f3; C = w3; m0 = (by - 168) * 128; }
    gemm_body<float, float, true>(As, Bs, A, B, bias, C, 256, m0, blockIdx.x * 128);
}

// softmax over s=16 for each (b,m,qpos); za bf16 [b][q][128] -> attn_t f32 [b][m][q][16]
__global__ __launch_bounds__(256) void softmax2(const short* __restrict__ za, float* __restrict__ attn_t)
{
    const int tid  = blockIdx.x * 256 + threadIdx.x;  // 131072
    const int qpos = tid & 4095;
    const int m    = (tid >> 12) & 7;
    const int b    = tid >> 15;
    const short* zp = za + ((size_t)(b * 4096 + qpos)) * 128 + m * 16;
    float v[16];
    #pragma unroll
    for (int i = 0; i < 16; ++i) v[i] = bf2f(zp[i]);
    float mx = v[0];
    #pragma unroll
    for (int i = 1; i < 16; ++i) mx = fmaxf(mx, v[i]);
    float s = 0.f;
    #pragma unroll
    for (int i = 0; i < 16; ++i) { v[i] = expf(v[i] - mx); s += v[i]; }
    const float inv = 1.f / s;
    float* op = attn_t + (((size_t)b * 8 + m) * 4096 + qpos) * 16;
    #pragma unroll
    for (int i = 0; i < 16; ++i) op[i] = v[i] * inv;
}

// sample: block per (b,qy,qx); tid = m*32 + l*8 + k*2 + hi.
// The 8-lane group (m,l) covers the 4 k-points x 2 halves of one sample
// cluster -> their bilinear taps hit the same ~6-9 cache lines (1 line =
// one pixel's 32-ch m-slice in f32), fetched once instead of 4x.
__global__ __launch_bounds__(256) void sample3(
    const short* __restrict__ zo,      // bf16 [b][qy][qx][256]
    const float* __restrict__ attn_t,  // f32 [b][m][4096][16]
    const float* __restrict__ ref,     // f32 [BS][64][64][2]
    const float* __restrict__ wp0, const float* __restrict__ wp1,
    const float* __restrict__ wp2, const float* __restrict__ wp3,
    float* __restrict__ outp)          // f32 [b][p][256]
{
    const int blk = blockIdx.x;          // b*4096 + qy*64 + qx
    const int qx = blk & 63;
    const int qy = (blk >> 6) & 63;
    const int b  = blk >> 12;
    const int t  = threadIdx.x;
    const int hi = t & 1;
    const int k  = (t >> 1) & 3;
    const int l  = (t >> 3) & 3;
    const int m  = t >> 5;

    const int ya = qy >> 2, yb = qy & 3;
    const int p  = (k << 10) | (qx << 4) | ya;
    const int c  = m * 32 + yb * 8 + l * 2 + hi;

    const int hw = 64 >> l;
    const float fw = (float)hw;
    const float* wp = (l == 0) ? wp0 : (l == 1) ? wp1 : (l == 2) ? wp2 : wp3;

    // learned offset (bf16 pair, 4B aligned)
    const unsigned off2 = *(const unsigned*)(zo + (size_t)blk * 256 + ((m * 4 + l) * 4 + k) * 2);
    const float offx = bf2f((short)(off2 & 0xffff));
    const float offy = bf2f((short)(off2 >> 16));

    const int rb = m & 3;
    const float2 rr = *(const float2*)(ref + ((size_t)(rb * 4096) + qy * 64 + qx) * 2);

    const float px  = rr.x * (fw - 1.f) + offx;
    const float py  = rr.y * (fw - 1.f) + offy;
    const float gx  = 2.f * px / (fw - 1.f) - 1.f;
    const float gy  = 2.f * py / (fw - 1.f) - 1.f;
    const float xim = (gx + 1.f) * (fw * 0.5f) - 0.5f;
    const float yim = (gy + 1.f) * (fw * 0.5f) - 0.5f;

    const float x0f = floorf(xim), y0f = floorf(yim);
    const float wx1 = xim - x0f, wy1 = yim - y0f;
    const float wx0 = 1.f - wx1, wy0 = 1.f - wy1;
    const int ix0 = (int)x0f, iy0 = (int)y0f;

    float w[16];
    {
        const float4* ap = (const float4*)(attn_t + (((size_t)b * 8 + m) * 4096 + p) * 16);
        #pragma unroll
        for (int i = 0; i < 4; ++i) {
            float4 f = ap[i];
            w[4*i] = f.x; w[4*i+1] = f.y; w[4*i+2] = f.z; w[4*i+3] = f.w;
        }
    }

    const size_t chb = (size_t)m * 32 + hi * 16;
    float r = 0.f;
    #pragma unroll
    for (int tap = 0; tap < 4; ++tap) {
        int iy = iy0 + (tap >> 1);
        int ix = ix0 + (tap & 1);
        const bool ok = (iy >= 0) & (iy < hw) & (ix >= 0) & (ix < hw);
        float wt = ((tap >> 1) ? wy1 : wy0) * ((tap & 1) ? wx1 : wx0);
        wt = ok ? wt : 0.f;
        iy = min(max(iy, 0), hw - 1);
        ix = min(max(ix, 0), hw - 1);
        const float4* tp = (const float4*)(wp + (((size_t)b * hw + iy) * hw + ix) * 256 + chb);
        const float4 t0 = tp[0], t1 = tp[1], t2 = tp[2], t3 = tp[3];
        float d = t0.x*w[0]  + t0.y*w[1]  + t0.z*w[2]  + t0.w*w[3]
                + t1.x*w[4]  + t1.y*w[5]  + t1.z*w[6]  + t1.w*w[7]
                + t2.x*w[8]  + t2.y*w[9]  + t2.z*w[10] + t2.w*w[11]
                + t3.x*w[12] + t3.y*w[13] + t3.z*w[14] + t3.w*w[15];
        r += wt * d;
    }

    outp[((size_t)b * 4096 + p) * 256 + c] = r;
}

extern "C" void kernel_launch(void* const* d_in, const int* in_sizes, int n_in,
                              void* d_out, int out_size, void* d_ws, size_t ws_size,
                              hipStream_t stream)
{
    const float* q   = (const float*)d_in[0];
    const float* ref = (const float*)d_in[1];
    const float* f0  = (const float*)d_in[2];
    const float* f1  = (const float*)d_in[3];
    const float* f2  = (const float*)d_in[4];
    const float* f3  = (const float*)d_in[5];
    const float* Wz  = (const float*)d_in[6];
    const float* bz  = (const float*)d_in[7];
    const float* Wo  = (const float*)d_in[8];
    const float* bo  = (const float*)d_in[9];
    const float* Wa  = (const float*)d_in[10];
    const float* ba  = (const float*)d_in[11];
    const float* Wp  = (const float*)d_in[12];
    const float* bp  = (const float*)d_in[13];
    const float* Wm  = (const float*)d_in[14];
    const float* bm  = (const float*)d_in[15];
    float* out = (float*)d_out;

    char* ws = (char*)d_ws;
    short* z      = (short*)(ws + ((size_t)0));         // bf16 8MB
    short* za     = (short*)(ws + ((size_t)8  << 20));  // bf16 4MB
    short* zo     = (short*)(ws + ((size_t)16 << 20));  // bf16 8MB
    float* attn_t = (float*)(ws + ((size_t)28 << 20));  // f32 8MB
    float* wp0    = (float*)(ws + ((size_t)36 << 20));  // f32 16MB
    float* wp1    = (float*)(ws + ((size_t)52 << 20));  // f32 4MB
    float* wp2    = (float*)(ws + ((size_t)56 << 20));  // f32 1MB
    float* wp3    = (float*)(ws + ((size_t)57 << 20));  // f32 0.25MB
    float* outp   = (float*)(ws + ((size_t)0));         // f32 16MB (z/za dead)

    const dim3 blk(256);

    // 1. z = bf16(q @ Wz + bz)
    gemm_mfma<float, short, false><<<dim3(2, 128), blk, 0, stream>>>(q, Wz, bz, z, 256);
    // 2. zo = bf16(z @ Wo + bo)
    gemm_mfma<short, short, false><<<dim3(2, 128), blk, 0, stream>>>(z, Wo, bo, zo, 256);
    // 3. za = bf16(z @ Wa + ba)
    gemm_mfma<short, short, false><<<dim3(1, 128), blk, 0, stream>>>(z, Wa, ba, za, 128);
    // 4. softmax -> attn_t [b][m][q][16]
    softmax2<<<dim3(512), blk, 0, stream>>>(za, attn_t);
    // 5. wp_l = feat_l @ Wp + bp (bf16x3 split), all levels in one dispatch
    gemm_wp_all<<<dim3(2, 170), blk, 0, stream>>>(f0, f1, f2, f3, Wp, bp, wp0, wp1, wp2, wp3);
    // 6. sampling -> out_pre (overwrites z/za region)
    sample3<<<dim3(16384), blk, 0, stream>>>(zo, attn_t, ref, wp0, wp1, wp2, wp3, outp);
    // 7. out = out_pre @ Wm + bm (bf16x3 split)
    gemm_mfma<float, float, true><<<dim3(2, 128), blk, 0, stream>>>(outp, Wm, bm, out, 256);
}